// Round 11
// baseline (92.439 us; speedup 1.0000x reference)
//
#include <hip/hip_runtime.h>
#include <math.h>

// RobustListLearner — DIAGNOSTIC ROUND (rep=4).
// Round-10 kernel repeated 4x (idempotent rewrites of identical values)
// so the kernel's duration (~119us) exceeds the harness's 85-93us poison
// fills and finally appears in the duration-sorted rocprof top-5 — every
// prior round's counters were the fill kernels', not ours.
// An opaque-zero VGPR (asm volatile v_mov_b32) is added to all LDS
// indices and the store index each rep so the compiler cannot hoist the
// compute out of the rep loop: VALU/LDS/stores all scale 4x together and
// counter RATIOS map directly onto the real (rep=1) kernel.
// Next round: revert to rep=1 + the fix indicated by {VALUBusy,
// FETCH_SIZE vs WRITE_SIZE, SQ_LDS_BANK_CONFLICT, write-BW}.
//
// Base kernel (passing, 29.7us, absmax 8192): one block per feature-pair,
// LDS row cache, arithmetic unranking of combinations(96,2), all-f32
// solve with Kahan det + f64 band fallback, plain dwordx4 stores.

#define NSAMP 96
#define NFEAT 64
#define MS 4560
#define MF 2016
#define HT (MS / 2)              // 2280 float4-slots per feature-pair
// jax pinv rcond = 10 * max(M,N) * eps_f32 = 20 * 2^-23
#define RCOND 2.384185791015625e-06
#define RC2 (RCOND * RCOND)      // 25*2^-42: exactly representable in f32
#define RC2F ((float)RC2)
#define BANDHI 1.00001f
#define BANDLO 0.99999f
#define REPS 4                   // DIAGNOSTIC multiplier

typedef float f32x4 __attribute__((ext_vector_type(4)));

__device__ __forceinline__ void solve2x2(
    float a00, float a01, float a10, float a11,
    float y0, float y1, float& w0, float& w1)
{
    // Kahan determinant: ~2ulp correct even under full cancellation
    float p    = a01 * a10;
    float e    = fmaf(a01, a10, -p);
    float detk = fmaf(a00, a11, -p) + e;

    float fr = fmaf(a11, a11, fmaf(a10, a10, fmaf(a01, a01, a00 * a00)));
    float d2 = detk * detk;
    float rc = RC2F * fr * fr;

    bool full;
    if (d2 > rc * BANDHI) {
        full = true;                            // provably matches f64 test
    } else if (d2 < rc * BANDLO) {
        full = false;                           // provably matches f64 test
    } else {
        // rare band (~0 in 9.2M): exact f64 test, bit-identical decisions
        double dA00 = (double)a00, dA01 = (double)a01;
        double dA10 = (double)a10, dA11 = (double)a11;
        double det = dA00 * dA11 - dA01 * dA10;
        double dfr = dA00 * dA00 + dA01 * dA01 + dA10 * dA10 + dA11 * dA11;
        full = det * det > RC2 * (dfr * dfr);
    }

    if (full) {
        float rd   = __builtin_amdgcn_rcpf(detk);   // v_rcp_f32, ~1ulp
        w0 = fmaf(a11, y0, -(a01 * y1)) * rd;
        w1 = fmaf(a00, y1, -(a10 * y0)) * rd;
    } else {
        // rank<=1: truncated pinv ~= A^T y / ||A||_F^2 (rare, values O(1))
        if (fr > 0.0f) {
            float rf = __builtin_amdgcn_rcpf(fr);
            w0 = fmaf(a00, y0, a10 * y1) * rf;
            w1 = fmaf(a01, y0, a11 * y1) * rf;
        } else {
            w0 = 0.0f;
            w1 = 0.0f;
        }
    }
}

// Unrank pair index p in [0, 4560) -> (i, j), i<j<96, lexicographic.
__device__ __forceinline__ void unrank_pair(int p, int& i, int& j)
{
    // 36481 - 8p: both integers < 2^24 -> exact f32 subtraction
    float disc = sqrtf((float)(36481 - 8 * p));
    int ie = (int)((191.0f - disc) * 0.5f);
    // correct to the exact floor: S(i) = i*(191-i)/2
    if (ie > 0 && ie * (191 - ie) / 2 > p) --ie;
    if ((ie + 1) * (190 - ie) / 2 <= p) ++ie;
    i = ie;
    j = ie + 1 + (p - ie * (191 - ie) / 2);
}

__global__ __launch_bounds__(256) void rll_kernel(
    const float* __restrict__ labels,     // [96]
    const float* __restrict__ features,   // [96][64]
    const int*   __restrict__ feat_idx,   // [2016][2]
    float* __restrict__ w_out,            // [TOTAL][2]
    float* __restrict__ c_out)            // [TOTAL][2] (float-encoded ints)
{
    __shared__ float sA[NSAMP];   // labels[i]*features[i][a]
    __shared__ float sB[NSAMP];   // labels[i]*features[i][b]
    __shared__ float sY[NSAMP];   // labels[i]-0.1f

    int f = blockIdx.x;                               // one f per block
    int2 ab = ((const int2*)feat_idx)[f];             // scalar load
    int tid = threadIdx.x;

    if (tid < NSAMP) {
        float l = labels[tid];
        sY[tid] = l - 0.1f;
        sA[tid] = l * features[tid * NFEAT + ab.x];
        sB[tid] = l * features[tid * NFEAT + ab.y];
    }
    __syncthreads();

    float af = (float)ab.x, bf = (float)ab.y;
    f32x4 cv = { af, bf, af, bf };
    size_t base = (size_t)f * HT;

    for (int rep = 0; rep < REPS; ++rep) {
        // opaque zero: volatile asm re-executes each rep, so every index
        // below is "loop-variant" and the whole body repeats 4x.
        int z;
        asm volatile("v_mov_b32 %0, 0" : "=v"(z));

        for (int t = tid; t < HT; t += 256) {
            int i0, j0;
            unrank_pair(2 * t, i0, j0);
            int i1 = i0, j1 = j0 + 1;
            if (j1 >= NSAMP) { i1 = i0 + 1; j1 = i1 + 1; }
            i0 += z; j0 += z; i1 += z; j1 += z;

            float w00, w01, w10, w11;
            solve2x2(sA[i0], sB[i0], sA[j0], sB[j0], sY[i0], sY[j0],
                     w00, w01);
            solve2x2(sA[i1], sB[i1], sA[j1], sB[j1], sY[i1], sY[j1],
                     w10, w11);

            size_t q = base + t + z;                  // float4 index
            f32x4 wv = { w00, w01, w10, w11 };
            *((f32x4*)w_out + q) = wv;                // plain dwordx4
            *((f32x4*)c_out + q) = cv;
        }
    }
}

extern "C" void kernel_launch(void* const* d_in, const int* in_sizes, int n_in,
                              void* d_out, int out_size, void* d_ws, size_t ws_size,
                              hipStream_t stream) {
    const float* labels     = (const float*)d_in[0];
    const float* features   = (const float*)d_in[1];
    // d_in[2] (sample_idx) is recomputed arithmetically on-device
    const int*   feat_idx   = (const int*)d_in[3];

    float* w_out = (float*)d_out;                       // TOTAL*2 floats
    float* c_out = (float*)d_out + (size_t)MS * MF * 2; // TOTAL*2 floats

    rll_kernel<<<MF, 256, 0, stream>>>(labels, features, feat_idx,
                                       w_out, c_out);
}

// Round 12
// 29.587 us; speedup vs baseline: 3.1244x; 3.1244x over previous
//
#include <hip/hip_runtime.h>
#include <math.h>

// RobustListLearner: for each (feature-pair f, sample-pair s) solve
// w = pinv(A) @ y for a 2x2 system, closed form.
//
// N=96, D=64, k=2 -> Ms=C(96,2)=4560, Mf=C(64,2)=2016, M=9,192,960 rows.
// Output: [weights: M*2 f32][col_indices: M*2 as f32 values].
//
// Ladder: 61 (naive) -> 39 (lfT transpose) -> 37.7 (float4 nt stores)
// -> 35.7 (all-f32 + f64 band fallback) -> 30.3 (fused, LDS row cache,
// plain stores) -> 29.7 (one block per f, arithmetic unranking).
// Round-11 rep=4 diagnostic (92.4us) established the endgame:
//   marginal rep = 20.9us for 147MB -> 7.0-7.2 TB/s marginal write rate,
//   AT/ABOVE the harness fill kernels' 6.3-6.9 TB/s. FETCH ~= 0,
//   LDS conflicts negligible, VALU 13.8us/rep hidden under 21us stores.
//   => 29.7us = ~22us roofline stores + ~8us fixed launch/ramp/drain.
// This file reverts the diagnostic to the rep=1 production kernel.
//
// Numerics:
//  - Kahan-fma determinant: ~2ulp rel even under cancellation.
//  - Rank decision: f32 test outside +-1e-5 band provably matches the
//    f64 test; inside the band recompute the exact f64 test
//    (bit-identical decisions to the validated f64 kernel of rounds 1-5).
//  - v_rcp_f32 (~1ulp): weight error <= ~0.09 abs vs 1.44e4 threshold.

#define NSAMP 96
#define NFEAT 64
#define MS 4560
#define MF 2016
#define HT (MS / 2)              // 2280 float4-slots per feature-pair
// jax pinv rcond = 10 * max(M,N) * eps_f32 = 20 * 2^-23
#define RCOND 2.384185791015625e-06
#define RC2 (RCOND * RCOND)      // 25*2^-42: exactly representable in f32
#define RC2F ((float)RC2)
#define BANDHI 1.00001f
#define BANDLO 0.99999f

typedef float f32x4 __attribute__((ext_vector_type(4)));

__device__ __forceinline__ void solve2x2(
    float a00, float a01, float a10, float a11,
    float y0, float y1, float& w0, float& w1)
{
    // Kahan determinant: ~2ulp correct even under full cancellation
    float p    = a01 * a10;
    float e    = fmaf(a01, a10, -p);
    float detk = fmaf(a00, a11, -p) + e;

    float fr = fmaf(a11, a11, fmaf(a10, a10, fmaf(a01, a01, a00 * a00)));
    float d2 = detk * detk;
    float rc = RC2F * fr * fr;

    bool full;
    if (d2 > rc * BANDHI) {
        full = true;                            // provably matches f64 test
    } else if (d2 < rc * BANDLO) {
        full = false;                           // provably matches f64 test
    } else {
        // rare band (~0 in 9.2M): exact f64 test, bit-identical decisions
        double dA00 = (double)a00, dA01 = (double)a01;
        double dA10 = (double)a10, dA11 = (double)a11;
        double det = dA00 * dA11 - dA01 * dA10;
        double dfr = dA00 * dA00 + dA01 * dA01 + dA10 * dA10 + dA11 * dA11;
        full = det * det > RC2 * (dfr * dfr);
    }

    if (full) {
        float rd   = __builtin_amdgcn_rcpf(detk);   // v_rcp_f32, ~1ulp
        w0 = fmaf(a11, y0, -(a01 * y1)) * rd;
        w1 = fmaf(a00, y1, -(a10 * y0)) * rd;
    } else {
        // rank<=1: truncated pinv ~= A^T y / ||A||_F^2 (rare, values O(1))
        if (fr > 0.0f) {
            float rf = __builtin_amdgcn_rcpf(fr);
            w0 = fmaf(a00, y0, a10 * y1) * rf;
            w1 = fmaf(a01, y0, a11 * y1) * rf;
        } else {
            w0 = 0.0f;
            w1 = 0.0f;
        }
    }
}

// Unrank pair index p in [0, 4560) -> (i, j), i<j<96, lexicographic.
__device__ __forceinline__ void unrank_pair(int p, int& i, int& j)
{
    // 36481 - 8p: both integers < 2^24 -> exact f32 subtraction
    float disc = sqrtf((float)(36481 - 8 * p));
    int ie = (int)((191.0f - disc) * 0.5f);
    // correct to the exact floor: S(i) = i*(191-i)/2
    if (ie > 0 && ie * (191 - ie) / 2 > p) --ie;
    if ((ie + 1) * (190 - ie) / 2 <= p) ++ie;
    i = ie;
    j = ie + 1 + (p - ie * (191 - ie) / 2);
}

// grid: 2016 blocks, one per feature-pair. Block builds its 288-float row
// cache in LDS once, then loops t over all 2280 float4-slots (9 rounds of
// 256). Hot loop global traffic: two coalesced dwordx4 stores ONLY.
__global__ __launch_bounds__(256) void rll_kernel(
    const float* __restrict__ labels,     // [96]
    const float* __restrict__ features,   // [96][64]
    const int*   __restrict__ feat_idx,   // [2016][2]
    float* __restrict__ w_out,            // [TOTAL][2]
    float* __restrict__ c_out)            // [TOTAL][2] (float-encoded ints)
{
    __shared__ float sA[NSAMP];   // labels[i]*features[i][a]
    __shared__ float sB[NSAMP];   // labels[i]*features[i][b]
    __shared__ float sY[NSAMP];   // labels[i]-0.1f

    int f = blockIdx.x;                               // one f per block
    int2 ab = ((const int2*)feat_idx)[f];             // scalar load
    int tid = threadIdx.x;

    if (tid < NSAMP) {
        float l = labels[tid];
        sY[tid] = l - 0.1f;
        // same expressions as prior rounds -> bit-identical values
        sA[tid] = l * features[tid * NFEAT + ab.x];
        sB[tid] = l * features[tid * NFEAT + ab.y];
    }
    __syncthreads();

    float af = (float)ab.x, bf = (float)ab.y;
    f32x4 cv = { af, bf, af, bf };
    size_t base = (size_t)f * HT;

    for (int t = tid; t < HT; t += 256) {
        // pairs p0 = 2t and its lexicographic successor p0+1
        int i0, j0;
        unrank_pair(2 * t, i0, j0);
        int i1 = i0, j1 = j0 + 1;
        if (j1 >= NSAMP) { i1 = i0 + 1; j1 = i1 + 1; }

        float w00, w01, w10, w11;
        solve2x2(sA[i0], sB[i0], sA[j0], sB[j0], sY[i0], sY[j0], w00, w01);
        solve2x2(sA[i1], sB[i1], sA[j1], sB[j1], sY[i1], sY[j1], w10, w11);

        size_t q = base + t;                          // float4 index
        f32x4 wv = { w00, w01, w10, w11 };
        *((f32x4*)w_out + q) = wv;                    // plain dwordx4
        *((f32x4*)c_out + q) = cv;
    }
}

extern "C" void kernel_launch(void* const* d_in, const int* in_sizes, int n_in,
                              void* d_out, int out_size, void* d_ws, size_t ws_size,
                              hipStream_t stream) {
    const float* labels     = (const float*)d_in[0];
    const float* features   = (const float*)d_in[1];
    // d_in[2] (sample_idx) is recomputed arithmetically on-device
    const int*   feat_idx   = (const int*)d_in[3];

    float* w_out = (float*)d_out;                       // TOTAL*2 floats
    float* c_out = (float*)d_out + (size_t)MS * MF * 2; // TOTAL*2 floats

    rll_kernel<<<MF, 256, 0, stream>>>(labels, features, feat_idx,
                                       w_out, c_out);
}